// Round 7
// baseline (602.270 us; speedup 1.0000x reference)
//
#include <hip/hip_runtime.h>

#define B_TOT 16384
#define HD 256
#define ID 128
#define BT 64    // two 32-row sub-tiles per block, interleaved per segment
#define NSTEP 8
#define YP 264   // y/u LDS pitch (f16)
#define XP 136
#define HP 260   // master-h LDS pitch (f32)

typedef float    f32x4  __attribute__((ext_vector_type(4)));
typedef float    f32x16 __attribute__((ext_vector_type(16)));
typedef _Float16 f16x8  __attribute__((ext_vector_type(8)));
typedef _Float16 f16x4  __attribute__((ext_vector_type(4)));
typedef _Float16 f16x2  __attribute__((ext_vector_type(2)));

__device__ __forceinline__ float fast_rcp(float x){ return __builtin_amdgcn_rcpf(x); }
__device__ __forceinline__ float fast_exp2(float x){ return __builtin_amdgcn_exp2f(x); }
__device__ __forceinline__ float fast_tanh(float x){
  return 1.0f - 2.0f*fast_rcp(1.0f + fast_exp2(x*2.8853900817779268f));
}
__device__ __forceinline__ float fast_sigmoid(float x){
  return fast_rcp(1.0f + fast_exp2(x*-1.4426950408889634f));
}

__global__ void cvt_f32_f16(const float* __restrict__ src, _Float16* __restrict__ dst, int n4){
  int i = blockIdx.x*256 + threadIdx.x;
  if (i < n4){
    float4 v = ((const float4*)src)[i];
    f16x4 t = {(_Float16)v.x, (_Float16)v.y, (_Float16)v.z, (_Float16)v.w};
    *(f16x4*)(dst + (size_t)i*4) = t;
  }
}

// acc element r: feat = 32*wv + 8*(r>>2) + 4*hh + (r&3), batch = l31
#define KPX(K,i) ((float)K[i][pk][hw])

// k-epilogue, 3-slot rank-compressed k-history (kd stays f32 in-epilogue):
//  slots: [0]=k1 [1]=k2 [2]=k3 until S3; at S3 store P1=a6.k->slot0,
//  P2=b.k partial->slot1 (slot2 dies); S4 extends P2; S5 closes.
#define EPI2(A2, YB, HS, K, DTV, SIDX)                                     \
  { _Pragma("unroll")                                                      \
    for (int g2 = 0; g2 < 4; ++g2){                                        \
      f32x4 hv = *(const f32x4*)(HS + hoff + 8*g2);                        \
      f16x4 yv; f32x4 hnv;                                                 \
      _Pragma("unroll")                                                    \
      for (int r3 = 0; r3 < 4; ++r3){                                      \
        const int r = g2*4 + r3; const int pk = r>>1; const int hw = r&1;  \
        float kd = (DTV)*(A2)[r];                                          \
        float yn;                                                          \
        if ((SIDX) == 0){                                                  \
          yn = hv[r3] + 0.2f*kd;                                           \
          K[0][pk][hw] = (_Float16)kd;                                     \
        } else if ((SIDX) == 1){                                           \
          yn = hv[r3] + 0.075f*KPX(K,0) + 0.225f*kd;                       \
          K[1][pk][hw] = (_Float16)kd;                                     \
        } else if ((SIDX) == 2){                                           \
          yn = hv[r3] + (44.0f/45.0f)*KPX(K,0) + (-56.0f/15.0f)*KPX(K,1)   \
             + (32.0f/9.0f)*kd;                                            \
          K[2][pk][hw] = (_Float16)kd;                                     \
        } else if ((SIDX) == 3){                                           \
          float k0 = KPX(K,0), k1 = KPX(K,1), k2 = KPX(K,2);               \
          yn = hv[r3] + (19372.0f/6561.0f)*k0 + (-25360.0f/2187.0f)*k1     \
             + (64448.0f/6561.0f)*k2 + (-212.0f/729.0f)*kd;                \
          float P1 = (9017.0f/3168.0f)*k0 + (-355.0f/33.0f)*k1             \
                   + (46732.0f/5247.0f)*k2 + (49.0f/176.0f)*kd;            \
          float P2 = (35.0f/384.0f)*k0 + (500.0f/1113.0f)*k2               \
                   + (125.0f/192.0f)*kd;                                   \
          K[0][pk][hw] = (_Float16)P1;                                     \
          K[1][pk][hw] = (_Float16)P2;                                     \
        } else if ((SIDX) == 4){                                           \
          float p1 = KPX(K,0), p2 = KPX(K,1);                              \
          yn = hv[r3] + p1 + (-5103.0f/18656.0f)*kd;                       \
          K[1][pk][hw] = (_Float16)(p2 + (-2187.0f/6784.0f)*kd);           \
        } else {                                                           \
          yn = hv[r3] + KPX(K,1) + (11.0f/84.0f)*kd;                       \
        }                                                                  \
        hnv[r3] = yn; yv[r3] = (_Float16)yn;                               \
      }                                                                    \
      if ((SIDX) == 5) *(f32x4*)(HS + hoff + 8*g2) = hnv;                  \
      *(f16x4*)(YB + yoff + 8*g2) = yv;                                    \
    }                                                                      \
  }

// tanh epilogue -> u buffer
#define EPI1(A1, UB)                                                       \
  { _Pragma("unroll")                                                      \
    for (int g2 = 0; g2 < 4; ++g2){                                        \
      f16x4 uv;                                                            \
      _Pragma("unroll")                                                    \
      for (int r3 = 0; r3 < 4; ++r3)                                       \
        uv[r3] = (_Float16)fast_tanh((A1)[g2*4 + r3]);                     \
      *(f16x4*)(UB + yoff + 8*g2) = uv;                                    \
    }                                                                      \
  }

// One RK stage for BOTH tiles: epiA's VALU overlaps gemmB's MFMA/LDS inside
// each half-segment (no barrier between them); one acc live at a time.
#define STAGE_DUAL(S)                                                      \
  { f32x16 a = gemm16(W1f, ylA, b1l); EPI1(a, ulA); }                      \
  { f32x16 a = gemm16(W1f, ylB, b1l); EPI1(a, ulB); }                      \
  __syncthreads();                                                         \
  { f32x16 a = gemm16(W2f, ulA, b2l); EPI2(a, ylA, hslA, kpkA, dtvA, S); } \
  { f32x16 a = gemm16(W2f, ulB, b2l); EPI2(a, ylB, hslB, kpkB, dtvB, S); } \
  __syncthreads();

__global__ __launch_bounds__(512, 2)
void ode_lstm(const float* __restrict__ inputs, const float* __restrict__ h0,
              const float* __restrict__ c0,     const float* __restrict__ ts,
              const float* __restrict__ b_ih,   const float* __restrict__ b_hh,
              const float* __restrict__ b1,     const float* __restrict__ b2,
              const _Float16* __restrict__ W1h, const _Float16* __restrict__ W2h,
              const _Float16* __restrict__ Wihh,const _Float16* __restrict__ Whhh,
              float* __restrict__ out)
{
  __shared__ __align__(16) _Float16 ylA[32*YP], ulA[32*YP];
  __shared__ __align__(16) _Float16 ylB[32*YP], ulB[32*YP];
  __shared__ __align__(16) float    hslA[32*HP], hslB[32*HP]; // master h (f32)
  __shared__ __align__(16) float    b1l[HD], b2l[HD], bsl[4*HD];
  __shared__ float dtl[BT];

  const int tid  = threadIdx.x;
  const int wv   = tid >> 6;        // 8 waves: feature strip 32*wv
  const int lane = tid & 63;
  const int l31  = lane & 31;       // batch row owned by this lane
  const int hh   = lane >> 5;       // k-half select; +4 feat offset in C/D
  const int row0 = blockIdx.x * BT;
  const int cb   = wv*32 + hh*4;
  const int yoff = l31*YP + cb;     // f16-elem offset (y/u buffers)
  const int hoff = l31*HP + cb;     // f32-elem offset (h buffers)

  if (tid < HD){ b1l[tid] = b1[tid]; b2l[tid] = b2[tid]; }
  bsl[tid]       = b_ih[tid]       + b_hh[tid];
  bsl[tid + 512] = b_ih[tid + 512] + b_hh[tid + 512];
  if (tid < BT) dtl[tid] = ts[row0 + tid] * (1.0f/NSTEP);

  // W1, W2 strips in regs for the whole RK45 loop (128 regs)
  f16x8 W1f[16], W2f[16];
  {
    const _Float16* w1p = W1h + (size_t)(wv*32 + l31)*HD + hh*8;
    const _Float16* w2p = W2h + (size_t)(wv*32 + l31)*HD + hh*8;
    #pragma unroll
    for (int kt = 0; kt < 16; ++kt){
      W1f[kt] = *(const f16x8*)(w1p + kt*16);
      W2f[kt] = *(const f16x8*)(w2p + kt*16);
    }
  }

  // h0 -> h LDS (f32) + y buffers (f16), both tiles
  #pragma unroll
  for (int g2 = 0; g2 < 4; ++g2){
    f32x4 ha = *(const f32x4*)(h0 + (size_t)(row0 + l31)*HD + cb + 8*g2);
    f32x4 hb = *(const f32x4*)(h0 + (size_t)(row0 + 32 + l31)*HD + cb + 8*g2);
    *(f32x4*)(hslA + hoff + 8*g2) = ha;
    *(f32x4*)(hslB + hoff + 8*g2) = hb;
    f16x4 ta = {(_Float16)ha[0],(_Float16)ha[1],(_Float16)ha[2],(_Float16)ha[3]};
    f16x4 tb = {(_Float16)hb[0],(_Float16)hb[1],(_Float16)hb[2],(_Float16)hb[3]};
    *(f16x4*)(ylA + yoff + 8*g2) = ta;
    *(f16x4*)(ylB + yoff + 8*g2) = tb;
  }
  __syncthreads();
  const float dtvA = dtl[l31], dtvB = dtl[32 + l31];

  // GEMM: single 16-deep chain (R6 proved 2-chain split is neutral), bias-init C
  auto gemm16 = [&](const f16x8 (&Wf)[16], const _Float16* __restrict__ act,
                    const float* __restrict__ bL)->f32x16{
    f32x16 a;
    #pragma unroll
    for (int g2 = 0; g2 < 4; ++g2){
      f32x4 bv = *(const f32x4*)(bL + cb + 8*g2);
      a[g2*4+0] = bv[0]; a[g2*4+1] = bv[1]; a[g2*4+2] = bv[2]; a[g2*4+3] = bv[3];
    }
    const _Float16* bp = act + l31*YP + hh*8;
    #pragma unroll
    for (int kt = 0; kt < 16; ++kt){
      f16x8 Bf = *(const f16x8*)(bp + kt*16);
      a = __builtin_amdgcn_mfma_f32_32x32x16_f16(Wf[kt], Bf, a, 0, 0, 0);
    }
    return a;
  };

  // ================= RK45 (Dormand-Prince), dual-tile =================
  #pragma unroll 1
  for (int step = 0; step < NSTEP; ++step){
    f16x2 kpkA[3][8], kpkB[3][8];   // rank-compressed k-history, 24 regs each
    STAGE_DUAL(0)
    STAGE_DUAL(1)
    STAGE_DUAL(2)
    STAGE_DUAL(3)
    STAGE_DUAL(4)
    STAGE_DUAL(5)
  }

  // ================= two weight-shared LSTM cells, per sub-tile =============
  // h LDS is dead (final h lives as f16 in ylA/ylB) -> reuse for x staging.
  _Float16* xA = (_Float16*)hslA;
  _Float16* xB = (_Float16*)hslB;

  #pragma unroll
  for (int it = 0; it < 4; ++it){
    int idx = tid + it*512;                 // 64 rows * 32 float4
    int r = idx >> 5, c4i = idx & 31;
    float4 v = ((const float4*)inputs)[(size_t)(row0 + r)*(ID/4) + c4i];
    f16x4 t = {(_Float16)v.x, (_Float16)v.y, (_Float16)v.z, (_Float16)v.w};
    _Float16* xd = (r < 32) ? xA : xB;
    *(f16x4*)(xd + (r & 31)*XP + c4i*4) = t;
  }
  __syncthreads();

  #pragma unroll 1
  for (int sb = 0; sb < 2; ++sb){
    const _Float16* xs  = sb ? xB  : xA;
    const _Float16* hod = sb ? ylB : ylA;   // h_ode (f16)
    _Float16*       h1  = sb ? ulB : ulA;   // h1 scratch (u-buffer is dead)
    const int rbase = row0 + sb*32;

    // x-part of gates (shared by both cells), bias-init with b_ih+b_hh
    f32x16 agx[4];
    #pragma unroll
    for (int g = 0; g < 4; ++g){
      #pragma unroll
      for (int g2 = 0; g2 < 4; ++g2){
        f32x4 bv = *(const f32x4*)(bsl + g*HD + cb + 8*g2);
        agx[g][g2*4+0] = bv[0]; agx[g][g2*4+1] = bv[1];
        agx[g][g2*4+2] = bv[2]; agx[g][g2*4+3] = bv[3];
      }
    }
    {
      const _Float16* bp = xs + l31*XP + hh*8;
      #pragma unroll 2
      for (int kt = 0; kt < 8; ++kt){
        f16x8 Bf = *(const f16x8*)(bp + kt*16);
        #pragma unroll
        for (int g = 0; g < 4; ++g){
          f16x8 Af = *(const f16x8*)(Wihh + (size_t)(g*HD + wv*32 + l31)*ID + kt*16 + hh*8);
          agx[g] = __builtin_amdgcn_mfma_f32_32x32x16_f16(Af, Bf, agx[g], 0, 0, 0);
        }
      }
    }
    f32x4 c4v[4];
    #pragma unroll
    for (int g2 = 0; g2 < 4; ++g2)
      c4v[g2] = *(const f32x4*)(c0 + (size_t)(rbase + l31)*HD + cb + 8*g2);

    #pragma unroll 1
    for (int cell = 0; cell < 2; ++cell){
      f32x16 ag[4];
      #pragma unroll
      for (int g = 0; g < 4; ++g) ag[g] = agx[g];
      const _Float16* bp = ((cell == 0) ? hod : (const _Float16*)h1) + l31*YP + hh*8;
      #pragma unroll 2
      for (int kt = 0; kt < 16; ++kt){
        f16x8 Bf = *(const f16x8*)(bp + kt*16);
        #pragma unroll
        for (int g = 0; g < 4; ++g){
          f16x8 Af = *(const f16x8*)(Whhh + (size_t)(g*HD + wv*32 + l31)*HD + kt*16 + hh*8);
          ag[g] = __builtin_amdgcn_mfma_f32_32x32x16_f16(Af, Bf, ag[g], 0, 0, 0);
        }
      }
      #pragma unroll
      for (int g2 = 0; g2 < 4; ++g2){
        f16x4 hv16; f32x4 ho, co;
        #pragma unroll
        for (int r3 = 0; r3 < 4; ++r3){
          const int r = g2*4 + r3;
          float iv = fast_sigmoid(ag[0][r]);
          float fv = fast_sigmoid(ag[1][r]);
          float gv = fast_tanh   (ag[2][r]);
          float ov = fast_sigmoid(ag[3][r]);
          float cn = fv*c4v[g2][r3] + iv*gv;
          c4v[g2][r3] = cn;
          float hn = ov*fast_tanh(cn);
          hv16[r3] = (_Float16)hn; ho[r3] = hn; co[r3] = cn;
        }
        if (cell == 0){
          *(f16x4*)(h1 + yoff + 8*g2) = hv16;        // h1 -> cell2 input
        } else {
          size_t o = (size_t)(rbase + l31)*HD + cb + 8*g2;
          *(f32x4*)(out + o) = ho;                   // h2
          *(f32x4*)(out + (size_t)B_TOT*HD + o) = co;// c2
        }
      }
      if (cell == 0) __syncthreads();
    }
  }
}

extern "C" void kernel_launch(void* const* d_in, const int* in_sizes, int n_in,
                              void* d_out, int out_size, void* d_ws, size_t ws_size,
                              hipStream_t stream) {
  (void)in_sizes; (void)n_in; (void)out_size; (void)ws_size;
  const float* inputs = (const float*)d_in[0];
  const float* h0     = (const float*)d_in[1];
  const float* c0     = (const float*)d_in[2];
  const float* ts     = (const float*)d_in[3];
  const float* W_ih   = (const float*)d_in[4];
  const float* W_hh   = (const float*)d_in[5];
  const float* b_ih   = (const float*)d_in[6];
  const float* b_hh   = (const float*)d_in[7];
  const float* W1     = (const float*)d_in[8];
  const float* b1     = (const float*)d_in[9];
  const float* W2     = (const float*)d_in[10];
  const float* b2     = (const float*)d_in[11];
  float* out = (float*)d_out;

  _Float16* wsh  = (_Float16*)d_ws;
  _Float16* W1h  = wsh;             // 65536
  _Float16* W2h  = wsh + 65536;     // 65536
  _Float16* Wihh = wsh + 131072;    // 131072
  _Float16* Whhh = wsh + 262144;    // 262144  (total 1 MB)

  cvt_f32_f16<<<64,  256, 0, stream>>>(W1,   W1h,  16384);
  cvt_f32_f16<<<64,  256, 0, stream>>>(W2,   W2h,  16384);
  cvt_f32_f16<<<128, 256, 0, stream>>>(W_ih, Wihh, 32768);
  cvt_f32_f16<<<256, 256, 0, stream>>>(W_hh, Whhh, 65536);

  ode_lstm<<<B_TOT/BT, 512, 0, stream>>>(inputs, h0, c0, ts, b_ih, b_hh, b1, b2,
                                         W1h, W2h, Wihh, Whhh, out);
}

// Round 8
// 476.667 us; speedup vs baseline: 1.2635x; 1.2635x over previous
//
#include <hip/hip_runtime.h>

#define B_TOT 16384
#define HD 256
#define ID 128
#define BT 64    // two 32-row sub-tiles per block, interleaved per segment
#define NSTEP 8
#define YP 264   // y/u LDS pitch (f16)
#define XP 136
#define HP 260   // master-h LDS pitch (f32)

typedef float    f32x4  __attribute__((ext_vector_type(4)));
typedef float    f32x16 __attribute__((ext_vector_type(16)));
typedef _Float16 f16x8  __attribute__((ext_vector_type(8)));
typedef _Float16 f16x4  __attribute__((ext_vector_type(4)));
typedef _Float16 f16x2  __attribute__((ext_vector_type(2)));

__device__ __forceinline__ float fast_rcp(float x){ return __builtin_amdgcn_rcpf(x); }
__device__ __forceinline__ float fast_exp2(float x){ return __builtin_amdgcn_exp2f(x); }
__device__ __forceinline__ float fast_tanh(float x){
  return 1.0f - 2.0f*fast_rcp(1.0f + fast_exp2(x*2.8853900817779268f));
}
__device__ __forceinline__ float fast_sigmoid(float x){
  return fast_rcp(1.0f + fast_exp2(x*-1.4426950408889634f));
}
__device__ __forceinline__ f16x2 h2(float c){
  f16x2 r; r[0] = (_Float16)c; r[1] = (_Float16)c; return r;
}

__global__ void cvt_f32_f16(const float* __restrict__ src, _Float16* __restrict__ dst, int n4){
  int i = blockIdx.x*256 + threadIdx.x;
  if (i < n4){
    float4 v = ((const float4*)src)[i];
    f16x4 t = {(_Float16)v.x, (_Float16)v.y, (_Float16)v.z, (_Float16)v.w};
    *(f16x4*)(dst + (size_t)i*4) = t;
  }
}

// acc element r: feat = 32*wv + 8*(r>>2) + 4*hh + (r&3), batch = l31
// k-history, 3-slot rank-compressed: slot0=k1 (tile B: in LDS), slot1=k2,
// slot2=k3; at S3 slot0<-P1=a6.k, slot1<-P2=b.k partial; S4 extends P2; S5 closes.
// Stages 0,1,2,4 use packed f16x2 math (k's are f16 anyway); stages 3,5 stay
// scalar f32 (large-coefficient cancellation / master-h accumulation).
#define EPI2X(A2, YB, HS, K0LD, K0ST, K1, K2, DTV, SIDX)                    \
  { _Pragma("unroll")                                                       \
    for (int g2 = 0; g2 < 4; ++g2){                                         \
      f32x4 hv = *(const f32x4*)((HS) + hoff + 8*g2);                       \
      f16x4 yv; f32x4 hnv;                                                  \
      _Pragma("unroll")                                                     \
      for (int p = 0; p < 2; ++p){                                          \
        const int pk = g2*2 + p;                                            \
        float kd0 = (DTV)*(A2)[g2*4+2*p+0];                                 \
        float kd1 = (DTV)*(A2)[g2*4+2*p+1];                                 \
        f16x2 kdp; kdp[0] = (_Float16)kd0; kdp[1] = (_Float16)kd1;          \
        f16x2 hp;  hp[0] = (_Float16)hv[2*p]; hp[1] = (_Float16)hv[2*p+1];  \
        f16x2 yp;                                                           \
        if ((SIDX) == 0){                                                   \
          yp = hp + h2(0.2f)*kdp;                                           \
          K0ST(pk, kdp);                                                    \
        } else if ((SIDX) == 1){                                            \
          yp = hp + h2(0.075f)*K0LD(pk) + h2(0.225f)*kdp;                   \
          K1[pk] = kdp;                                                     \
        } else if ((SIDX) == 2){                                            \
          yp = hp + h2(44.0f/45.0f)*K0LD(pk) + h2(-56.0f/15.0f)*K1[pk]      \
             + h2(32.0f/9.0f)*kdp;                                          \
          K2[pk] = kdp;                                                     \
        } else if ((SIDX) == 3){                                            \
          f16x2 k0v = K0LD(pk), k1v = K1[pk], k2v = K2[pk];                 \
          f16x2 P1, P2;                                                     \
          _Pragma("unroll")                                                 \
          for (int e = 0; e < 2; ++e){                                      \
            float k0f = (float)k0v[e], k1f = (float)k1v[e];                 \
            float k2f = (float)k2v[e];                                      \
            float kdf = e ? kd1 : kd0;                                      \
            float yn = hv[2*p+e] + (19372.0f/6561.0f)*k0f                   \
                     + (-25360.0f/2187.0f)*k1f + (64448.0f/6561.0f)*k2f     \
                     + (-212.0f/729.0f)*kdf;                                \
            yp[e] = (_Float16)yn;                                           \
            P1[e] = (_Float16)((9017.0f/3168.0f)*k0f + (-355.0f/33.0f)*k1f  \
                   + (46732.0f/5247.0f)*k2f + (49.0f/176.0f)*kdf);          \
            P2[e] = (_Float16)((35.0f/384.0f)*k0f + (500.0f/1113.0f)*k2f    \
                   + (125.0f/192.0f)*kdf);                                  \
          }                                                                 \
          K0ST(pk, P1);                                                     \
          K1[pk] = P2;                                                      \
        } else if ((SIDX) == 4){                                            \
          yp = hp + K0LD(pk) + h2(-5103.0f/18656.0f)*kdp;                   \
          K1[pk] = K1[pk] + h2(-2187.0f/6784.0f)*kdp;                       \
        } else {                                                            \
          f16x2 p2v = K1[pk];                                               \
          float hn0 = hv[2*p+0] + (float)p2v[0] + (11.0f/84.0f)*kd0;        \
          float hn1 = hv[2*p+1] + (float)p2v[1] + (11.0f/84.0f)*kd1;        \
          hnv[2*p+0] = hn0; hnv[2*p+1] = hn1;                               \
          yp[0] = (_Float16)hn0; yp[1] = (_Float16)hn1;                     \
        }                                                                   \
        yv[2*p+0] = yp[0]; yv[2*p+1] = yp[1];                               \
      }                                                                     \
      if ((SIDX) == 5) *(f32x4*)((HS) + hoff + 8*g2) = hnv;                 \
      *(f16x4*)((YB) + yoff + 8*g2) = yv;                                   \
    }                                                                       \
  }

// k-slot-0 accessors: tile A in regs, tile B in LDS (per-thread private,
// lane-consecutive layout [pk][tid] -> conflict-free, no barriers needed)
#define KA0LD(pk)    kA0[pk]
#define KA0ST(pk, v) (kA0[pk] = (v))
#define KB0LD(pk)    kslB0[pk][tid]
#define KB0ST(pk, v) (kslB0[pk][tid] = (v))

// tanh epilogue -> u buffer
#define EPI1(A1, UB)                                                       \
  { _Pragma("unroll")                                                      \
    for (int g2 = 0; g2 < 4; ++g2){                                        \
      f16x4 uv;                                                            \
      _Pragma("unroll")                                                    \
      for (int r3 = 0; r3 < 4; ++r3)                                       \
        uv[r3] = (_Float16)fast_tanh((A1)[g2*4 + r3]);                     \
      *(f16x4*)(UB + yoff + 8*g2) = uv;                                    \
    }                                                                      \
  }

// One RK stage for BOTH tiles: epiX's VALU overlaps gemmY's MFMA/LDS inside
// each half-segment (no barrier between them).
#define STAGE_DUAL(S)                                                      \
  { f32x16 a = gemm16(W1f, ylA, b1l); EPI1(a, ulA); }                      \
  { f32x16 a = gemm16(W1f, ylB, b1l); EPI1(a, ulB); }                      \
  __syncthreads();                                                         \
  { f32x16 a = gemm16(W2f, ulA, b2l);                                      \
    EPI2X(a, ylA, hslA, KA0LD, KA0ST, kA1, kA2, dtvA, S); }                \
  { f32x16 a = gemm16(W2f, ulB, b2l);                                      \
    EPI2X(a, ylB, hslB, KB0LD, KB0ST, kB1, kB2, dtvB, S); }                \
  __syncthreads();

__global__ __launch_bounds__(512, 2)
void ode_lstm(const float* __restrict__ inputs, const float* __restrict__ h0,
              const float* __restrict__ c0,     const float* __restrict__ ts,
              const float* __restrict__ b_ih,   const float* __restrict__ b_hh,
              const float* __restrict__ b1,     const float* __restrict__ b2,
              const _Float16* __restrict__ W1h, const _Float16* __restrict__ W2h,
              const _Float16* __restrict__ Wihh,const _Float16* __restrict__ Whhh,
              float* __restrict__ out)
{
  __shared__ __align__(16) _Float16 ylA[32*YP], ulA[32*YP];
  __shared__ __align__(16) _Float16 ylB[32*YP], ulB[32*YP];
  __shared__ __align__(16) float    hslA[32*HP], hslB[32*HP]; // master h (f32)
  __shared__ __align__(16) float    b1l[HD], b2l[HD], bsl[4*HD];
  __shared__ __align__(8)  f16x2    kslB0[8][512];  // tile-B k-slot0, 16 KB
  __shared__ float dtl[BT];

  const int tid  = threadIdx.x;
  const int wv   = tid >> 6;        // 8 waves: feature strip 32*wv
  const int lane = tid & 63;
  const int l31  = lane & 31;       // batch row owned by this lane
  const int hh   = lane >> 5;       // k-half select; +4 feat offset in C/D
  const int row0 = blockIdx.x * BT;
  const int cb   = wv*32 + hh*4;
  const int yoff = l31*YP + cb;     // f16-elem offset (y/u buffers)
  const int hoff = l31*HP + cb;     // f32-elem offset (h buffers)

  if (tid < HD){ b1l[tid] = b1[tid]; b2l[tid] = b2[tid]; }
  bsl[tid]       = b_ih[tid]       + b_hh[tid];
  bsl[tid + 512] = b_ih[tid + 512] + b_hh[tid + 512];
  if (tid < BT) dtl[tid] = ts[row0 + tid] * (1.0f/NSTEP);

  // W1, W2 strips in regs for the whole RK45 loop (128 regs)
  f16x8 W1f[16], W2f[16];
  {
    const _Float16* w1p = W1h + (size_t)(wv*32 + l31)*HD + hh*8;
    const _Float16* w2p = W2h + (size_t)(wv*32 + l31)*HD + hh*8;
    #pragma unroll
    for (int kt = 0; kt < 16; ++kt){
      W1f[kt] = *(const f16x8*)(w1p + kt*16);
      W2f[kt] = *(const f16x8*)(w2p + kt*16);
    }
  }

  // h0 -> h LDS (f32) + y buffers (f16), both tiles
  #pragma unroll
  for (int g2 = 0; g2 < 4; ++g2){
    f32x4 ha = *(const f32x4*)(h0 + (size_t)(row0 + l31)*HD + cb + 8*g2);
    f32x4 hb = *(const f32x4*)(h0 + (size_t)(row0 + 32 + l31)*HD + cb + 8*g2);
    *(f32x4*)(hslA + hoff + 8*g2) = ha;
    *(f32x4*)(hslB + hoff + 8*g2) = hb;
    f16x4 ta = {(_Float16)ha[0],(_Float16)ha[1],(_Float16)ha[2],(_Float16)ha[3]};
    f16x4 tb = {(_Float16)hb[0],(_Float16)hb[1],(_Float16)hb[2],(_Float16)hb[3]};
    *(f16x4*)(ylA + yoff + 8*g2) = ta;
    *(f16x4*)(ylB + yoff + 8*g2) = tb;
  }
  __syncthreads();
  const float dtvA = dtl[l31], dtvB = dtl[32 + l31];

  // GEMM: single 16-deep chain, bias-init C
  auto gemm16 = [&](const f16x8 (&Wf)[16], const _Float16* __restrict__ act,
                    const float* __restrict__ bL)->f32x16{
    f32x16 a;
    #pragma unroll
    for (int g2 = 0; g2 < 4; ++g2){
      f32x4 bv = *(const f32x4*)(bL + cb + 8*g2);
      a[g2*4+0] = bv[0]; a[g2*4+1] = bv[1]; a[g2*4+2] = bv[2]; a[g2*4+3] = bv[3];
    }
    const _Float16* bp = act + l31*YP + hh*8;
    #pragma unroll
    for (int kt = 0; kt < 16; ++kt){
      f16x8 Bf = *(const f16x8*)(bp + kt*16);
      a = __builtin_amdgcn_mfma_f32_32x32x16_f16(Wf[kt], Bf, a, 0, 0, 0);
    }
    return a;
  };

  // ================= RK45 (Dormand-Prince), dual-tile =================
  #pragma unroll 1
  for (int step = 0; step < NSTEP; ++step){
    f16x2 kA0[8], kA1[8], kA2[8];   // tile-A k-history, 24 regs
    f16x2 kB1[8], kB2[8];           // tile-B slots 1,2 (slot 0 in LDS), 16 regs
    STAGE_DUAL(0)
    STAGE_DUAL(1)
    STAGE_DUAL(2)
    STAGE_DUAL(3)
    STAGE_DUAL(4)
    STAGE_DUAL(5)
  }

  // ================= two weight-shared LSTM cells, per sub-tile =============
  // h LDS is dead (final h lives as f16 in ylA/ylB) -> reuse for x staging.
  _Float16* xA = (_Float16*)hslA;
  _Float16* xB = (_Float16*)hslB;

  #pragma unroll
  for (int it = 0; it < 4; ++it){
    int idx = tid + it*512;                 // 64 rows * 32 float4
    int r = idx >> 5, c4i = idx & 31;
    float4 v = ((const float4*)inputs)[(size_t)(row0 + r)*(ID/4) + c4i];
    f16x4 t = {(_Float16)v.x, (_Float16)v.y, (_Float16)v.z, (_Float16)v.w};
    _Float16* xd = (r < 32) ? xA : xB;
    *(f16x4*)(xd + (r & 31)*XP + c4i*4) = t;
  }
  __syncthreads();

  #pragma unroll 1
  for (int sb = 0; sb < 2; ++sb){
    const _Float16* xs  = sb ? xB  : xA;
    const _Float16* hod = sb ? ylB : ylA;   // h_ode (f16)
    _Float16*       h1  = sb ? ulB : ulA;   // h1 scratch (u-buffer is dead)
    const int rbase = row0 + sb*32;

    // x-part of gates (shared by both cells), bias-init with b_ih+b_hh
    f32x16 agx[4];
    #pragma unroll
    for (int g = 0; g < 4; ++g){
      #pragma unroll
      for (int g2 = 0; g2 < 4; ++g2){
        f32x4 bv = *(const f32x4*)(bsl + g*HD + cb + 8*g2);
        agx[g][g2*4+0] = bv[0]; agx[g][g2*4+1] = bv[1];
        agx[g][g2*4+2] = bv[2]; agx[g][g2*4+3] = bv[3];
      }
    }
    {
      const _Float16* bp = xs + l31*XP + hh*8;
      #pragma unroll 2
      for (int kt = 0; kt < 8; ++kt){
        f16x8 Bf = *(const f16x8*)(bp + kt*16);
        #pragma unroll
        for (int g = 0; g < 4; ++g){
          f16x8 Af = *(const f16x8*)(Wihh + (size_t)(g*HD + wv*32 + l31)*ID + kt*16 + hh*8);
          agx[g] = __builtin_amdgcn_mfma_f32_32x32x16_f16(Af, Bf, agx[g], 0, 0, 0);
        }
      }
    }
    f32x4 c4v[4];
    #pragma unroll
    for (int g2 = 0; g2 < 4; ++g2)
      c4v[g2] = *(const f32x4*)(c0 + (size_t)(rbase + l31)*HD + cb + 8*g2);

    #pragma unroll 1
    for (int cell = 0; cell < 2; ++cell){
      f32x16 ag[4];
      #pragma unroll
      for (int g = 0; g < 4; ++g) ag[g] = agx[g];
      const _Float16* bp = ((cell == 0) ? hod : (const _Float16*)h1) + l31*YP + hh*8;
      #pragma unroll 2
      for (int kt = 0; kt < 16; ++kt){
        f16x8 Bf = *(const f16x8*)(bp + kt*16);
        #pragma unroll
        for (int g = 0; g < 4; ++g){
          f16x8 Af = *(const f16x8*)(Whhh + (size_t)(g*HD + wv*32 + l31)*HD + kt*16 + hh*8);
          ag[g] = __builtin_amdgcn_mfma_f32_32x32x16_f16(Af, Bf, ag[g], 0, 0, 0);
        }
      }
      #pragma unroll
      for (int g2 = 0; g2 < 4; ++g2){
        f16x4 hv16; f32x4 ho, co;
        #pragma unroll
        for (int r3 = 0; r3 < 4; ++r3){
          const int r = g2*4 + r3;
          float iv = fast_sigmoid(ag[0][r]);
          float fv = fast_sigmoid(ag[1][r]);
          float gv = fast_tanh   (ag[2][r]);
          float ov = fast_sigmoid(ag[3][r]);
          float cn = fv*c4v[g2][r3] + iv*gv;
          c4v[g2][r3] = cn;
          float hn = ov*fast_tanh(cn);
          hv16[r3] = (_Float16)hn; ho[r3] = hn; co[r3] = cn;
        }
        if (cell == 0){
          *(f16x4*)(h1 + yoff + 8*g2) = hv16;        // h1 -> cell2 input
        } else {
          size_t o = (size_t)(rbase + l31)*HD + cb + 8*g2;
          *(f32x4*)(out + o) = ho;                   // h2
          *(f32x4*)(out + (size_t)B_TOT*HD + o) = co;// c2
        }
      }
      if (cell == 0) __syncthreads();
    }
  }
}

extern "C" void kernel_launch(void* const* d_in, const int* in_sizes, int n_in,
                              void* d_out, int out_size, void* d_ws, size_t ws_size,
                              hipStream_t stream) {
  (void)in_sizes; (void)n_in; (void)out_size; (void)ws_size;
  const float* inputs = (const float*)d_in[0];
  const float* h0     = (const float*)d_in[1];
  const float* c0     = (const float*)d_in[2];
  const float* ts     = (const float*)d_in[3];
  const float* W_ih   = (const float*)d_in[4];
  const float* W_hh   = (const float*)d_in[5];
  const float* b_ih   = (const float*)d_in[6];
  const float* b_hh   = (const float*)d_in[7];
  const float* W1     = (const float*)d_in[8];
  const float* b1     = (const float*)d_in[9];
  const float* W2     = (const float*)d_in[10];
  const float* b2     = (const float*)d_in[11];
  float* out = (float*)d_out;

  _Float16* wsh  = (_Float16*)d_ws;
  _Float16* W1h  = wsh;             // 65536
  _Float16* W2h  = wsh + 65536;     // 65536
  _Float16* Wihh = wsh + 131072;    // 131072
  _Float16* Whhh = wsh + 262144;    // 262144  (total 1 MB)

  cvt_f32_f16<<<64,  256, 0, stream>>>(W1,   W1h,  16384);
  cvt_f32_f16<<<64,  256, 0, stream>>>(W2,   W2h,  16384);
  cvt_f32_f16<<<128, 256, 0, stream>>>(W_ih, Wihh, 32768);
  cvt_f32_f16<<<256, 256, 0, stream>>>(W_hh, Whhh, 65536);

  ode_lstm<<<B_TOT/BT, 512, 0, stream>>>(inputs, h0, c0, ts, b_ih, b_hh, b1, b2,
                                         W1h, W2h, Wihh, Whhh, out);
}